// Round 18
// baseline (79.988 us; speedup 1.0000x reference)
//
#include <hip/hip_runtime.h>
#include <math.h>

#define BB 8
#define TT 2048
#define NE 1024
#define HH 64
#define BT (BB * TT)

typedef __attribute__((ext_vector_type(8))) short s8v;   // 8 x bf16 fragment
typedef __attribute__((ext_vector_type(4))) float f4v;   // 4 x f32 accum

__device__ inline unsigned short f2bf(float f) {
  union { float f; unsigned u; } v;
  v.f = f;
  unsigned r = (v.u + 0x7FFFu + ((v.u >> 16) & 1u)) >> 16;  // RNE
  return (unsigned short)r;
}

__device__ inline unsigned short f2bf_trunc(float f) {
  union { float f; unsigned u; } v;
  v.f = f;
  return (unsigned short)(v.u >> 16);
}

// packed f32x2 -> bf16x2 (RNE), src0 -> low16, src1 -> high16
__device__ inline unsigned cvtpk(float lo, float hi) {
  unsigned r;
  asm("v_cvt_pk_bf16_f32 %0, %1, %2" : "=v"(r) : "v"(lo), "v"(hi));
  return r;
}

// async global->LDS, 16B per lane; l is the wave-uniform base (HW adds lane*16)
__device__ inline void glds16(const unsigned short* g, unsigned short* l) {
  __builtin_amdgcn_global_load_lds(
      (const __attribute__((address_space(1))) unsigned*)g,
      (__attribute__((address_space(3))) unsigned*)l, 16, 0, 0);
}

// ---------------------------------------------------------------------------
// Kernel 0: W [1024][64] f32 x3 -> WTf, FRAGMENT-MAJOR bf16 (unchanged)
// ---------------------------------------------------------------------------
__global__ __launch_bounds__(256) void conv_wt_kernel(
    const float* __restrict__ Wq, const float* __restrict__ Wk,
    const float* __restrict__ Wv, unsigned short* __restrict__ WTf) {
  const int idx = blockIdx.x * 256 + threadIdx.x;  // 0..24575
  const int cb = idx >> 11;
  const int ks = (idx >> 6) & 31;
  const int lane = idx & 63;
  const int lr = lane & 15, lg = lane >> 4;
  const int col = cb * 16 + lr;
  const int m = col >> 6, h = col & 63;
  const int n0 = ks * 32 + lg * 8;
  const float* W = (m == 0) ? Wq : (m == 1) ? Wk : Wv;
  unsigned short v[8];
#pragma unroll
  for (int j = 0; j < 8; ++j) v[j] = f2bf(W[(size_t)(n0 + j) * HH + h]);
  *reinterpret_cast<uint4*>(WTf + (size_t)idx * 8) =
      *reinterpret_cast<const uint4*>(v);
}

// ---------------------------------------------------------------------------
// Kernel 1: QKV projection — counted-vmcnt pipeline (r11, ~25 µs, unchanged)
// ---------------------------------------------------------------------------
__global__ __launch_bounds__(256, 5) void qkv_proj_mfma(
    const float* __restrict__ x, const unsigned short* __restrict__ WTf,
    unsigned short* __restrict__ Q, unsigned short* __restrict__ K,
    unsigned short* __restrict__ VT) {
  __shared__ __align__(16) unsigned short Bbuf[2][6144];  // 12 KB each
  __shared__ __align__(16) unsigned short Abuf[3][640];   // [16][40] bf16 each

  const int tid = threadIdx.x;
  const int lane = tid & 63;
  const int w = tid >> 6;
  const int lr = lane & 15, lg = lane >> 4;
  const int row0 = blockIdx.x * 16;

  const int arow = tid >> 4, aunit = tid & 15;
  const float* __restrict__ xsrc = x + (size_t)(row0 + arow) * NE + aunit * 2;

  f4v acc[3];
#pragma unroll
  for (int c = 0; c < 3; ++c) acc[c] = (f4v)0.f;

  float2 La[2];

  auto ISSUE_B = [&](int buf, int t) {
#pragma unroll
    for (int j = 0; j < 3; ++j) {
      const int cb = w * 3 + j;
      glds16(WTf + (size_t)(cb * 32 + t) * 512 + lane * 8, &Bbuf[buf][cb * 512]);
    }
  };

  La[0] = *reinterpret_cast<const float2*>(xsrc);
  La[1] = *reinterpret_cast<const float2*>(xsrc + 32);
  ISSUE_B(0, 0);
  *reinterpret_cast<unsigned*>(&Abuf[0][arow * 40 + aunit * 2]) =
      cvtpk(La[0].x, La[0].y);
  La[0] = *reinterpret_cast<const float2*>(xsrc + 2 * 32);
  *reinterpret_cast<unsigned*>(&Abuf[1][arow * 40 + aunit * 2]) =
      cvtpk(La[1].x, La[1].y);
  asm volatile("s_waitcnt vmcnt(1) lgkmcnt(0)" ::: "memory");
  __builtin_amdgcn_s_barrier();
  __builtin_amdgcn_sched_barrier(0);

#pragma unroll
  for (int t = 0; t < 32; ++t) {
    const int cur = t & 1;
    if (t + 1 < 32) ISSUE_B(cur ^ 1, t + 1);
    __builtin_amdgcn_sched_barrier(0);
    if (t + 3 < 32)
      La[(t + 3) & 1] = *reinterpret_cast<const float2*>(xsrc + (t + 3) * 32);
    __builtin_amdgcn_sched_barrier(0);
    const s8v a = *reinterpret_cast<const s8v*>(&Abuf[t % 3][lr * 40 + lg * 8]);
#pragma unroll
    for (int j = 0; j < 3; ++j) {
      const int cb = w * 3 + j;
      const s8v b = *reinterpret_cast<const s8v*>(&Bbuf[cur][cb * 512 + lane * 8]);
      acc[j] = __builtin_amdgcn_mfma_f32_16x16x32_bf16(a, b, acc[j], 0, 0, 0);
    }
    if (t + 2 < 32)
      *reinterpret_cast<unsigned*>(&Abuf[(t + 2) % 3][arow * 40 + aunit * 2]) =
          cvtpk(La[t & 1].x, La[t & 1].y);
    if (t + 1 < 32) {
      if (t + 3 < 32) {
        asm volatile("s_waitcnt vmcnt(1) lgkmcnt(0)" ::: "memory");
      } else {
        asm volatile("s_waitcnt vmcnt(0) lgkmcnt(0)" ::: "memory");
      }
      __builtin_amdgcn_s_barrier();
      __builtin_amdgcn_sched_barrier(0);
    }
  }

  const float QSCL = 0.18033688011112042f;  // 0.125 * log2(e)
#pragma unroll
  for (int c = 0; c < 3; ++c) {
    const int col = (w * 3 + c) * 16 + lr;
    const int m = col >> 6;
    const int h = col & 63;
#pragma unroll
    for (int r = 0; r < 4; ++r) {
      const int rr = row0 + lg * 4 + r;
      if (m == 0) {
        Q[(size_t)rr * HH + h] = f2bf(acc[c][r] * QSCL);
      } else if (m == 1) {
        K[(size_t)rr * HH + h] = f2bf(acc[c][r]);
      } else {
        const int bb2 = rr >> 11, tt2 = rr & (TT - 1);
        VT[((size_t)bb2 * HH + h) * TT + tt2] = f2bf(acc[c][r]);
      }
    }
  }
}

// ---------------------------------------------------------------------------
// Kernel 2: causal flash attention — r14 structure, KBLK=128.
//   Grid 1024 (b,qt), 4 waves split this qt's k-range in 128-WIDE tiles.
//   Per 128-tile the serial fixed costs (K-load stall, 16-shuffle max chain,
//   16-shuffle sum chain, defer-max check, P-LDS turnaround) are paid ONCE
//   for 2x the k-elements of the old 64-tile -> per-k serial cost halves.
//   V staged in two 64-halves: vfrA under softmax, vfrB issued after
//   vfrA[0] dies (hidden under PV-half0) -> peak live ~110 VGPR, no spill.
//   In-block 4-wave combine (r14 verbatim); wave0 always owns >= 1 tile so
//   ms is finite (no NaN path).
// ---------------------------------------------------------------------------
__global__ __launch_bounds__(256, 4) void flash_attn_mfma(
    const unsigned short* __restrict__ Q, const unsigned short* __restrict__ K,
    const unsigned short* __restrict__ VT, float* __restrict__ out) {
  __shared__ unsigned short pl[4][16][72];
  __shared__ float ol[4][16][64];
  __shared__ float ml[4][16];
  __shared__ float ll[4][16];

  const int tid = threadIdx.x;
  const int lane = tid & 63;
  const int w = tid >> 6;
  const int lr = lane & 15;
  const int lg = lane >> 4;
  const int bid = blockIdx.x;
  const int b = bid & 7;
  const int qt = 127 - (bid >> 3);  // LPT: longest q-tiles dispatched first
  const int q0 = qt * 16;
  const size_t rowbase = (size_t)b * TT;

  const int nkt = (qt >> 3) + 1;    // 128-wide k-tiles covering rows < q0+16
  const int base = nkt >> 2, rem = nkt & 3;
  const int t0 = w * base + (w < rem ? w : rem);
  const int cnt = base + (w < rem ? 1 : 0);

  const s8v qf0 = *reinterpret_cast<const s8v*>(
      Q + (rowbase + q0 + lr) * HH + lg * 8);
  const s8v qf1 = *reinterpret_cast<const s8v*>(
      Q + (rowbase + q0 + lr) * HH + 32 + lg * 8);

  f4v o[4];
#pragma unroll
  for (int n = 0; n < 4; ++n) o[n] = (f4v)0.f;
  float mrow[4], lrow[4];
#pragma unroll
  for (int r = 0; r < 4; ++r) { mrow[r] = -INFINITY; lrow[r] = 0.f; }

  const unsigned short* const Vb = VT + (size_t)b * HH * TT;

  for (int kt = t0; kt < t0 + cnt; ++kt) {
    const int k0 = kt * 128;
    f4v s[8];
#pragma unroll
    for (int nk = 0; nk < 8; ++nk) s[nk] = (f4v)0.f;
    __builtin_amdgcn_s_setprio(1);
#pragma unroll
    for (int nk = 0; nk < 8; ++nk) {
      const unsigned short* kp = K + (rowbase + k0 + 16 * nk + lr) * HH + lg * 8;
      const s8v kf0 = *reinterpret_cast<const s8v*>(kp);
      const s8v kf1 = *reinterpret_cast<const s8v*>(kp + 32);
      s[nk] = __builtin_amdgcn_mfma_f32_16x16x32_bf16(qf0, kf0, s[nk], 0, 0, 0);
      s[nk] = __builtin_amdgcn_mfma_f32_16x16x32_bf16(qf1, kf1, s[nk], 0, 0, 0);
    }
    __builtin_amdgcn_s_setprio(0);
    // V half A (k0..k0+63): latency hides under softmax
    s8v vfrA[2][4];
#pragma unroll
    for (int kh = 0; kh < 2; ++kh)
#pragma unroll
      for (int n = 0; n < 4; ++n)
        vfrA[kh][n] = *reinterpret_cast<const s8v*>(
            Vb + (size_t)(16 * n + lr) * TT + k0 + kh * 32 + lg * 8);

    // causal mask: only the last tile intersects the diagonal
    if (kt == nkt - 1) {
#pragma unroll
      for (int nk = 0; nk < 8; ++nk) {
        const int kk = k0 + 16 * nk + lr;
#pragma unroll
        for (int r = 0; r < 4; ++r) {
          const int qq = q0 + lg * 4 + r;
          if (kk > qq) s[nk][r] = -INFINITY;
        }
      }
    }

    // row max over 128 k (local 8-frag max chain, ONE 16-lane reduce) + T13
    float mx_[4];
    float grow = -INFINITY;
#pragma unroll
    for (int r = 0; r < 4; ++r) {
      float mx = fmaxf(fmaxf(fmaxf(s[0][r], s[1][r]), fmaxf(s[2][r], s[3][r])),
                       fmaxf(fmaxf(s[4][r], s[5][r]), fmaxf(s[6][r], s[7][r])));
#pragma unroll
      for (int off = 1; off < 16; off <<= 1)
        mx = fmaxf(mx, __shfl_xor(mx, off));
      mx_[r] = mx;
      grow = fmaxf(grow, mx - mrow[r]);
    }
    if (!__all(grow <= 8.f)) {  // wave-uniform rescale (rare after warmup)
#pragma unroll
      for (int r = 0; r < 4; ++r) {
        const float mnew = fmaxf(mrow[r], mx_[r]);
        const float scl = exp2f(mrow[r] - mnew);
        mrow[r] = mnew;
        lrow[r] *= scl;
#pragma unroll
        for (int n = 0; n < 4; ++n) o[n][r] *= scl;
      }
    }
    // p = exp2(s - m) (bounded by 2^8), ONE shuffle row-sum for 128 k
#pragma unroll
    for (int r = 0; r < 4; ++r) {
      float rs = 0.f;
#pragma unroll
      for (int nk = 0; nk < 8; ++nk) {
        const float p = exp2f(s[nk][r] - mrow[r]);
        s[nk][r] = p;
        rs += p;
      }
#pragma unroll
      for (int off = 1; off < 16; off <<= 1)
        rs += __shfl_xor(rs, off);
      lrow[r] += rs;
    }

    // ---- P half 0 (k0..k0+63): store s[0..3], PV with vfrA
#pragma unroll
    for (int nk = 0; nk < 4; ++nk)
#pragma unroll
      for (int r = 0; r < 4; ++r)
        pl[w][lg * 4 + r][16 * nk + lr] = f2bf_trunc(s[nk][r]);
    s8v vfrB[2][4];
    {
      // kh = 0
      const ushort4 plo = *reinterpret_cast<const ushort4*>(&pl[w][lr][lg * 8]);
      const ushort4 phi =
          *reinterpret_cast<const ushort4*>(&pl[w][lr][lg * 8 + 4]);
      s8v pa;
      pa[0] = plo.x; pa[1] = plo.y; pa[2] = plo.z; pa[3] = plo.w;
      pa[4] = phi.x; pa[5] = phi.y; pa[6] = phi.z; pa[7] = phi.w;
      __builtin_amdgcn_s_setprio(1);
#pragma unroll
      for (int n = 0; n < 4; ++n)
        o[n] = __builtin_amdgcn_mfma_f32_16x16x32_bf16(pa, vfrA[0][n], o[n], 0, 0, 0);
      __builtin_amdgcn_s_setprio(0);
      // issue V half B now (vfrA[0] dead): hides under PV kh=1 + half1 store
#pragma unroll
      for (int kh = 0; kh < 2; ++kh)
#pragma unroll
        for (int n = 0; n < 4; ++n)
          vfrB[kh][n] = *reinterpret_cast<const s8v*>(
              Vb + (size_t)(16 * n + lr) * TT + k0 + 64 + kh * 32 + lg * 8);
      // kh = 1
      const ushort4 qlo =
          *reinterpret_cast<const ushort4*>(&pl[w][lr][32 + lg * 8]);
      const ushort4 qhi =
          *reinterpret_cast<const ushort4*>(&pl[w][lr][32 + lg * 8 + 4]);
      s8v pb;
      pb[0] = qlo.x; pb[1] = qlo.y; pb[2] = qlo.z; pb[3] = qlo.w;
      pb[4] = qhi.x; pb[5] = qhi.y; pb[6] = qhi.z; pb[7] = qhi.w;
      __builtin_amdgcn_s_setprio(1);
#pragma unroll
      for (int n = 0; n < 4; ++n)
        o[n] = __builtin_amdgcn_mfma_f32_16x16x32_bf16(pb, vfrA[1][n], o[n], 0, 0, 0);
      __builtin_amdgcn_s_setprio(0);
    }

    // ---- P half 1 (k0+64..k0+127): store s[4..7], PV with vfrB
#pragma unroll
    for (int nk = 0; nk < 4; ++nk)
#pragma unroll
      for (int r = 0; r < 4; ++r)
        pl[w][lg * 4 + r][16 * nk + lr] = f2bf_trunc(s[4 + nk][r]);
#pragma unroll
    for (int kh = 0; kh < 2; ++kh) {
      const int pc = kh * 32 + lg * 8;
      const ushort4 plo = *reinterpret_cast<const ushort4*>(&pl[w][lr][pc]);
      const ushort4 phi = *reinterpret_cast<const ushort4*>(&pl[w][lr][pc + 4]);
      s8v pa;
      pa[0] = plo.x; pa[1] = plo.y; pa[2] = plo.z; pa[3] = plo.w;
      pa[4] = phi.x; pa[5] = phi.y; pa[6] = phi.z; pa[7] = phi.w;
      __builtin_amdgcn_s_setprio(1);
#pragma unroll
      for (int n = 0; n < 4; ++n)
        o[n] = __builtin_amdgcn_mfma_f32_16x16x32_bf16(pa, vfrB[kh][n], o[n], 0, 0, 0);
      __builtin_amdgcn_s_setprio(0);
    }
  }

  // publish per-wave partials
#pragma unroll
  for (int n = 0; n < 4; ++n)
#pragma unroll
    for (int r = 0; r < 4; ++r) ol[w][lg * 4 + r][16 * n + lr] = o[n][r];
  if (lr == 0) {
#pragma unroll
    for (int r = 0; r < 4; ++r) {
      ml[w][lg * 4 + r] = mrow[r];
      ll[w][lg * 4 + r] = lrow[r];
    }
  }
  __syncthreads();

  // combine: thread -> (row = tid>>4, 4 cols at (tid&15)*4)
  // wave0 always has >= 1 tile -> ms finite; empty waves contribute w=0.
  const int row = tid >> 4;
  const int c0 = (tid & 15) * 4;
  float m0 = ml[0][row], m1 = ml[1][row], m2 = ml[2][row], m3 = ml[3][row];
  const float ms = fmaxf(fmaxf(m0, m1), fmaxf(m2, m3));
  const float w0 = exp2f(m0 - ms), w1 = exp2f(m1 - ms);
  const float w2 = exp2f(m2 - ms), w3 = exp2f(m3 - ms);
  const float lsum = w0 * ll[0][row] + w1 * ll[1][row] +
                     w2 * ll[2][row] + w3 * ll[3][row];
  float4 osum;
  osum.x = w0 * ol[0][row][c0 + 0] + w1 * ol[1][row][c0 + 0] +
           w2 * ol[2][row][c0 + 0] + w3 * ol[3][row][c0 + 0];
  osum.y = w0 * ol[0][row][c0 + 1] + w1 * ol[1][row][c0 + 1] +
           w2 * ol[2][row][c0 + 1] + w3 * ol[3][row][c0 + 1];
  osum.z = w0 * ol[0][row][c0 + 2] + w1 * ol[1][row][c0 + 2] +
           w2 * ol[2][row][c0 + 2] + w3 * ol[3][row][c0 + 2];
  osum.w = w0 * ol[0][row][c0 + 3] + w1 * ol[1][row][c0 + 3] +
           w2 * ol[2][row][c0 + 3] + w3 * ol[3][row][c0 + 3];
  const float inv = 1.0f / lsum;
  float4 res;
  res.x = osum.x * inv; res.y = osum.y * inv;
  res.z = osum.z * inv; res.w = osum.w * inv;
  *reinterpret_cast<float4*>(out + (rowbase + q0 + row) * HH + c0) = res;
}

extern "C" void kernel_launch(void* const* d_in, const int* in_sizes, int n_in,
                              void* d_out, int out_size, void* d_ws, size_t ws_size,
                              hipStream_t stream) {
  const float* x  = (const float*)d_in[0];
  const float* Wk = (const float*)d_in[1];
  const float* Wq = (const float*)d_in[2];
  const float* Wv = (const float*)d_in[3];
  float* out = (float*)d_out;

  unsigned short* ws = (unsigned short*)d_ws;
  unsigned short* Q  = ws;                           // BT*HH bf16
  unsigned short* K  = ws + (size_t)BT * HH;         // BT*HH bf16
  unsigned short* VT = ws + 2 * (size_t)BT * HH;     // B*HH*TT bf16
  unsigned short* WT = ws + 3 * (size_t)BT * HH;     // 192*1024 bf16 (frag-major)

  conv_wt_kernel<<<96, 256, 0, stream>>>(Wq, Wk, Wv, WT);
  qkv_proj_mfma<<<1024, 256, 0, stream>>>(x, WT, Q, K, VT);
  flash_attn_mfma<<<1024, 256, 0, stream>>>(Q, K, VT, out);
}

// Round 19
// 69.029 us; speedup vs baseline: 1.1588x; 1.1588x over previous
//
#include <hip/hip_runtime.h>
#include <math.h>

#define BB 8
#define TT 2048
#define NE 1024
#define HH 64
#define BT (BB * TT)

typedef __attribute__((ext_vector_type(8))) short s8v;   // 8 x bf16 fragment
typedef __attribute__((ext_vector_type(4))) float f4v;   // 4 x f32 accum

__device__ inline unsigned short f2bf(float f) {
  union { float f; unsigned u; } v;
  v.f = f;
  unsigned r = (v.u + 0x7FFFu + ((v.u >> 16) & 1u)) >> 16;  // RNE
  return (unsigned short)r;
}

__device__ inline unsigned short f2bf_trunc(float f) {
  union { float f; unsigned u; } v;
  v.f = f;
  return (unsigned short)(v.u >> 16);
}

// packed f32x2 -> bf16x2 (RNE), src0 -> low16, src1 -> high16
__device__ inline unsigned cvtpk(float lo, float hi) {
  unsigned r;
  asm("v_cvt_pk_bf16_f32 %0, %1, %2" : "=v"(r) : "v"(lo), "v"(hi));
  return r;
}

// async global->LDS, 16B per lane; l is the wave-uniform base (HW adds lane*16)
__device__ inline void glds16(const unsigned short* g, unsigned short* l) {
  __builtin_amdgcn_global_load_lds(
      (const __attribute__((address_space(1))) unsigned*)g,
      (__attribute__((address_space(3))) unsigned*)l, 16, 0, 0);
}

// ---------------------------------------------------------------------------
// Kernel 0: W [1024][64] f32 x3 -> WTf, FRAGMENT-MAJOR bf16 (unchanged)
// ---------------------------------------------------------------------------
__global__ __launch_bounds__(256) void conv_wt_kernel(
    const float* __restrict__ Wq, const float* __restrict__ Wk,
    const float* __restrict__ Wv, unsigned short* __restrict__ WTf) {
  const int idx = blockIdx.x * 256 + threadIdx.x;  // 0..24575
  const int cb = idx >> 11;
  const int ks = (idx >> 6) & 31;
  const int lane = idx & 63;
  const int lr = lane & 15, lg = lane >> 4;
  const int col = cb * 16 + lr;
  const int m = col >> 6, h = col & 63;
  const int n0 = ks * 32 + lg * 8;
  const float* W = (m == 0) ? Wq : (m == 1) ? Wk : Wv;
  unsigned short v[8];
#pragma unroll
  for (int j = 0; j < 8; ++j) v[j] = f2bf(W[(size_t)(n0 + j) * HH + h]);
  *reinterpret_cast<uint4*>(WTf + (size_t)idx * 8) =
      *reinterpret_cast<const uint4*>(v);
}

// ---------------------------------------------------------------------------
// Kernel 1: QKV projection — counted-vmcnt pipeline (r11, ~25 µs, unchanged)
// ---------------------------------------------------------------------------
__global__ __launch_bounds__(256, 5) void qkv_proj_mfma(
    const float* __restrict__ x, const unsigned short* __restrict__ WTf,
    unsigned short* __restrict__ Q, unsigned short* __restrict__ K,
    unsigned short* __restrict__ VT) {
  __shared__ __align__(16) unsigned short Bbuf[2][6144];  // 12 KB each
  __shared__ __align__(16) unsigned short Abuf[3][640];   // [16][40] bf16 each

  const int tid = threadIdx.x;
  const int lane = tid & 63;
  const int w = tid >> 6;
  const int lr = lane & 15, lg = lane >> 4;
  const int row0 = blockIdx.x * 16;

  const int arow = tid >> 4, aunit = tid & 15;
  const float* __restrict__ xsrc = x + (size_t)(row0 + arow) * NE + aunit * 2;

  f4v acc[3];
#pragma unroll
  for (int c = 0; c < 3; ++c) acc[c] = (f4v)0.f;

  float2 La[2];

  auto ISSUE_B = [&](int buf, int t) {
#pragma unroll
    for (int j = 0; j < 3; ++j) {
      const int cb = w * 3 + j;
      glds16(WTf + (size_t)(cb * 32 + t) * 512 + lane * 8, &Bbuf[buf][cb * 512]);
    }
  };

  La[0] = *reinterpret_cast<const float2*>(xsrc);
  La[1] = *reinterpret_cast<const float2*>(xsrc + 32);
  ISSUE_B(0, 0);
  *reinterpret_cast<unsigned*>(&Abuf[0][arow * 40 + aunit * 2]) =
      cvtpk(La[0].x, La[0].y);
  La[0] = *reinterpret_cast<const float2*>(xsrc + 2 * 32);
  *reinterpret_cast<unsigned*>(&Abuf[1][arow * 40 + aunit * 2]) =
      cvtpk(La[1].x, La[1].y);
  asm volatile("s_waitcnt vmcnt(1) lgkmcnt(0)" ::: "memory");
  __builtin_amdgcn_s_barrier();
  __builtin_amdgcn_sched_barrier(0);

#pragma unroll
  for (int t = 0; t < 32; ++t) {
    const int cur = t & 1;
    if (t + 1 < 32) ISSUE_B(cur ^ 1, t + 1);
    __builtin_amdgcn_sched_barrier(0);
    if (t + 3 < 32)
      La[(t + 3) & 1] = *reinterpret_cast<const float2*>(xsrc + (t + 3) * 32);
    __builtin_amdgcn_sched_barrier(0);
    const s8v a = *reinterpret_cast<const s8v*>(&Abuf[t % 3][lr * 40 + lg * 8]);
#pragma unroll
    for (int j = 0; j < 3; ++j) {
      const int cb = w * 3 + j;
      const s8v b = *reinterpret_cast<const s8v*>(&Bbuf[cur][cb * 512 + lane * 8]);
      acc[j] = __builtin_amdgcn_mfma_f32_16x16x32_bf16(a, b, acc[j], 0, 0, 0);
    }
    if (t + 2 < 32)
      *reinterpret_cast<unsigned*>(&Abuf[(t + 2) % 3][arow * 40 + aunit * 2]) =
          cvtpk(La[t & 1].x, La[t & 1].y);
    if (t + 1 < 32) {
      if (t + 3 < 32) {
        asm volatile("s_waitcnt vmcnt(1) lgkmcnt(0)" ::: "memory");
      } else {
        asm volatile("s_waitcnt vmcnt(0) lgkmcnt(0)" ::: "memory");
      }
      __builtin_amdgcn_s_barrier();
      __builtin_amdgcn_sched_barrier(0);
    }
  }

  const float QSCL = 0.18033688011112042f;  // 0.125 * log2(e)
#pragma unroll
  for (int c = 0; c < 3; ++c) {
    const int col = (w * 3 + c) * 16 + lr;
    const int m = col >> 6;
    const int h = col & 63;
#pragma unroll
    for (int r = 0; r < 4; ++r) {
      const int rr = row0 + lg * 4 + r;
      if (m == 0) {
        Q[(size_t)rr * HH + h] = f2bf(acc[c][r] * QSCL);
      } else if (m == 1) {
        K[(size_t)rr * HH + h] = f2bf(acc[c][r]);
      } else {
        const int bb2 = rr >> 11, tt2 = rr & (TT - 1);
        VT[((size_t)bb2 * HH + h) * TT + tt2] = f2bf(acc[c][r]);
      }
    }
  }
}

// ---------------------------------------------------------------------------
// Kernel 2: causal flash attention — 512 threads (8 waves), k split 8 ways.
//   Grid 1024 (b,qt) x 4 blocks/CU x 8 waves = 32 waves/CU (HW max).
//   Longest wave chain: 4 tiles (r14: 8).  Per-wave body = r7 VERBATIM
//   (VGPR 64, no extra live state — lesson of r8/r9/r13/r18 spills).
//   P-buffer aliases the wave's own ol slice (r17-proven); LDS 33.3 KB.
//   In-block 8-way combine; wave0 always non-empty -> ms finite.
// ---------------------------------------------------------------------------
__global__ __launch_bounds__(512, 4) void flash_attn_mfma(
    const unsigned short* __restrict__ Q, const unsigned short* __restrict__ K,
    const unsigned short* __restrict__ VT, float* __restrict__ out) {
  __shared__ float ol[8][16][64];   // 32 KB; ol[w] doubles as wave-w P-buffer
  __shared__ float ml[8][16];
  __shared__ float ll[8][16];

  const int tid = threadIdx.x;
  const int lane = tid & 63;
  const int w = tid >> 6;           // 0..7
  const int lr = lane & 15;
  const int lg = lane >> 4;
  const int bid = blockIdx.x;
  const int b = bid & 7;
  const int qt = 127 - (bid >> 3);  // LPT
  const int q0 = qt * 16;
  const size_t rowbase = (size_t)b * TT;

  unsigned short* const plw = reinterpret_cast<unsigned short*>(&ol[w][0][0]);
  // plw[row*72 + col], 2304 B < 4096 B of ol[w]

  const int nt = (qt >> 2) + 1;     // k-tiles of 64
  const int base = nt >> 3, rem = nt & 7;
  const int t0 = w * base + (w < rem ? w : rem);
  const int cnt = base + (w < rem ? 1 : 0);

  const s8v qf0 = *reinterpret_cast<const s8v*>(
      Q + (rowbase + q0 + lr) * HH + lg * 8);
  const s8v qf1 = *reinterpret_cast<const s8v*>(
      Q + (rowbase + q0 + lr) * HH + 32 + lg * 8);

  f4v o[4];
#pragma unroll
  for (int n = 0; n < 4; ++n) o[n] = (f4v)0.f;
  float mrow[4], lrow[4];
#pragma unroll
  for (int r = 0; r < 4; ++r) { mrow[r] = -INFINITY; lrow[r] = 0.f; }

  for (int kt = t0; kt < t0 + cnt; ++kt) {
    const int k0 = kt * 64;
    f4v s[4];
#pragma unroll
    for (int nk = 0; nk < 4; ++nk) s[nk] = (f4v)0.f;
    __builtin_amdgcn_s_setprio(1);
#pragma unroll
    for (int nk = 0; nk < 4; ++nk) {
      const unsigned short* kp = K + (rowbase + k0 + 16 * nk + lr) * HH + lg * 8;
      const s8v kf0 = *reinterpret_cast<const s8v*>(kp);
      const s8v kf1 = *reinterpret_cast<const s8v*>(kp + 32);
      s[nk] = __builtin_amdgcn_mfma_f32_16x16x32_bf16(qf0, kf0, s[nk], 0, 0, 0);
      s[nk] = __builtin_amdgcn_mfma_f32_16x16x32_bf16(qf1, kf1, s[nk], 0, 0, 0);
    }
    __builtin_amdgcn_s_setprio(0);
    // hoist V loads: L2 latency hides under softmax
    s8v vfr[2][4];
#pragma unroll
    for (int kh = 0; kh < 2; ++kh)
#pragma unroll
      for (int n = 0; n < 4; ++n)
        vfr[kh][n] = *reinterpret_cast<const s8v*>(
            VT + ((size_t)b * HH + 16 * n + lr) * TT + k0 + kh * 32 + lg * 8);

    // scores already log2-domain (Q pre-scaled); mask only on diag tile
    if (kt == nt - 1) {
#pragma unroll
      for (int nk = 0; nk < 4; ++nk) {
        const int kk = k0 + 16 * nk + lr;
#pragma unroll
        for (int r = 0; r < 4; ++r) {
          const int qq = q0 + lg * 4 + r;
          if (kk > qq) s[nk][r] = -INFINITY;
        }
      }
    }

    // row max (16-lane reduce) + T13 defer-max decision
    float mx_[4];
    float grow = -INFINITY;
#pragma unroll
    for (int r = 0; r < 4; ++r) {
      float mx = fmaxf(fmaxf(s[0][r], s[1][r]), fmaxf(s[2][r], s[3][r]));
#pragma unroll
      for (int off = 1; off < 16; off <<= 1)
        mx = fmaxf(mx, __shfl_xor(mx, off));
      mx_[r] = mx;
      grow = fmaxf(grow, mx - mrow[r]);
    }
    if (!__all(grow <= 8.f)) {  // wave-uniform rescale (rare after warmup)
#pragma unroll
      for (int r = 0; r < 4; ++r) {
        const float mnew = fmaxf(mrow[r], mx_[r]);
        const float scl = exp2f(mrow[r] - mnew);
        mrow[r] = mnew;
        lrow[r] *= scl;
#pragma unroll
        for (int n = 0; n < 4; ++n) o[n][r] *= scl;
      }
    }
    // p = exp2(s - m) (bounded by 2^8), shuffle row-sum
#pragma unroll
    for (int r = 0; r < 4; ++r) {
      float rs = 0.f;
#pragma unroll
      for (int nk = 0; nk < 4; ++nk) {
        const float p = exp2f(s[nk][r] - mrow[r]);
        s[nk][r] = p;
        rs += p;
      }
#pragma unroll
      for (int off = 1; off < 16; off <<= 1)
        rs += __shfl_xor(rs, off);
      lrow[r] += rs;
    }
    // P: D-layout -> per-wave LDS (aliased; wave-private, no barrier)
#pragma unroll
    for (int nk = 0; nk < 4; ++nk)
#pragma unroll
      for (int r = 0; r < 4; ++r)
        plw[(lg * 4 + r) * 72 + 16 * nk + lr] = f2bf_trunc(s[nk][r]);
    // PV
#pragma unroll
    for (int kh = 0; kh < 2; ++kh) {
      const int pc = kh * 32 + lg * 8;
      const ushort4 plo = *reinterpret_cast<const ushort4*>(&plw[lr * 72 + pc]);
      const ushort4 phi =
          *reinterpret_cast<const ushort4*>(&plw[lr * 72 + pc + 4]);
      s8v pa;
      pa[0] = plo.x; pa[1] = plo.y; pa[2] = plo.z; pa[3] = plo.w;
      pa[4] = phi.x; pa[5] = phi.y; pa[6] = phi.z; pa[7] = phi.w;
      __builtin_amdgcn_s_setprio(1);
#pragma unroll
      for (int n = 0; n < 4; ++n)
        o[n] = __builtin_amdgcn_mfma_f32_16x16x32_bf16(pa, vfr[kh][n], o[n], 0, 0, 0);
      __builtin_amdgcn_s_setprio(0);
    }
  }

  // publish per-wave partials (ol[w] overwrites this wave's own P-buffer)
  __syncthreads();
#pragma unroll
  for (int n = 0; n < 4; ++n)
#pragma unroll
    for (int r = 0; r < 4; ++r) ol[w][lg * 4 + r][16 * n + lr] = o[n][r];
  if (lr == 0) {
#pragma unroll
    for (int r = 0; r < 4; ++r) {
      ml[w][lg * 4 + r] = mrow[r];
      ll[w][lg * 4 + r] = lrow[r];
    }
  }
  __syncthreads();

  // 8-way combine: 512 threads -> (row = tid>>5, 2 cols at (tid&31)*2)
  const int row = tid >> 5;
  const int c0 = (tid & 31) * 2;
  float mw[8];
#pragma unroll
  for (int i = 0; i < 8; ++i) mw[i] = ml[i][row];
  float ms = mw[0];
#pragma unroll
  for (int i = 1; i < 8; ++i) ms = fmaxf(ms, mw[i]);
  // wave0 always has >= 1 tile -> ms finite; empty waves get weight 0
  float wt[8];
  float lsum = 0.f;
#pragma unroll
  for (int i = 0; i < 8; ++i) {
    wt[i] = exp2f(mw[i] - ms);
    lsum += wt[i] * ll[i][row];
  }
  float o0 = 0.f, o1 = 0.f;
#pragma unroll
  for (int i = 0; i < 8; ++i) {
    o0 += wt[i] * ol[i][row][c0 + 0];
    o1 += wt[i] * ol[i][row][c0 + 1];
  }
  const float inv = 1.0f / lsum;
  float2 res;
  res.x = o0 * inv;
  res.y = o1 * inv;
  *reinterpret_cast<float2*>(out + (rowbase + q0 + row) * HH + c0) = res;
}

extern "C" void kernel_launch(void* const* d_in, const int* in_sizes, int n_in,
                              void* d_out, int out_size, void* d_ws, size_t ws_size,
                              hipStream_t stream) {
  const float* x  = (const float*)d_in[0];
  const float* Wk = (const float*)d_in[1];
  const float* Wq = (const float*)d_in[2];
  const float* Wv = (const float*)d_in[3];
  float* out = (float*)d_out;

  unsigned short* ws = (unsigned short*)d_ws;
  unsigned short* Q  = ws;                           // BT*HH bf16
  unsigned short* K  = ws + (size_t)BT * HH;         // BT*HH bf16
  unsigned short* VT = ws + 2 * (size_t)BT * HH;     // B*HH*TT bf16
  unsigned short* WT = ws + 3 * (size_t)BT * HH;     // 192*1024 bf16 (frag-major)

  conv_wt_kernel<<<96, 256, 0, stream>>>(Wq, Wk, Wv, WT);
  qkv_proj_mfma<<<1024, 256, 0, stream>>>(x, WT, Q, K, VT);
  flash_attn_mfma<<<1024, 512, 0, stream>>>(Q, K, VT, out);
}

// Round 20
// 67.775 us; speedup vs baseline: 1.1802x; 1.0185x over previous
//
#include <hip/hip_runtime.h>
#include <math.h>

#define BB 8
#define TT 2048
#define NE 1024
#define HH 64
#define BT (BB * TT)

typedef __attribute__((ext_vector_type(8))) short s8v;   // 8 x bf16 fragment
typedef __attribute__((ext_vector_type(4))) float f4v;   // 4 x f32 accum

__device__ inline unsigned short f2bf(float f) {
  union { float f; unsigned u; } v;
  v.f = f;
  unsigned r = (v.u + 0x7FFFu + ((v.u >> 16) & 1u)) >> 16;  // RNE
  return (unsigned short)r;
}

__device__ inline unsigned short f2bf_trunc(float f) {
  union { float f; unsigned u; } v;
  v.f = f;
  return (unsigned short)(v.u >> 16);
}

// packed f32x2 -> bf16x2 (RNE), src0 -> low16, src1 -> high16
__device__ inline unsigned cvtpk(float lo, float hi) {
  unsigned r;
  asm("v_cvt_pk_bf16_f32 %0, %1, %2" : "=v"(r) : "v"(lo), "v"(hi));
  return r;
}

// async global->LDS, 16B per lane; l is the wave-uniform base (HW adds lane*16)
__device__ inline void glds16(const unsigned short* g, unsigned short* l) {
  __builtin_amdgcn_global_load_lds(
      (const __attribute__((address_space(1))) unsigned*)g,
      (__attribute__((address_space(3))) unsigned*)l, 16, 0, 0);
}

// ---------------------------------------------------------------------------
// Kernel 0: W [1024][64] f32 x3 -> WTf, FRAGMENT-MAJOR bf16 (unchanged)
// ---------------------------------------------------------------------------
__global__ __launch_bounds__(256) void conv_wt_kernel(
    const float* __restrict__ Wq, const float* __restrict__ Wk,
    const float* __restrict__ Wv, unsigned short* __restrict__ WTf) {
  const int idx = blockIdx.x * 256 + threadIdx.x;  // 0..24575
  const int cb = idx >> 11;
  const int ks = (idx >> 6) & 31;
  const int lane = idx & 63;
  const int lr = lane & 15, lg = lane >> 4;
  const int col = cb * 16 + lr;
  const int m = col >> 6, h = col & 63;
  const int n0 = ks * 32 + lg * 8;
  const float* W = (m == 0) ? Wq : (m == 1) ? Wk : Wv;
  unsigned short v[8];
#pragma unroll
  for (int j = 0; j < 8; ++j) v[j] = f2bf(W[(size_t)(n0 + j) * HH + h]);
  *reinterpret_cast<uint4*>(WTf + (size_t)idx * 8) =
      *reinterpret_cast<const uint4*>(v);
}

// ---------------------------------------------------------------------------
// Kernel 1: QKV projection — counted-vmcnt pipeline, HALF-BARRIER version.
//   Insight: B staging is WAVE-PRIVATE (each wave glds-writes and ds_reads
//   only cols w*3..w*3+2) -> the barrier only protects the Abuf handoff.
//   Abuf deepened to 4 slots: writer(t)->reader(t+2) and reader(t)->
//   writer(t+2) both span >= 2 tile-ends -> s_barrier only after ODD tiles
//   (16 barriers, was 32).  Per-tile counted vmcnt(1) (newest A-load flies,
//   B glds drained) kept every tile — that is all B needs.
//   sched_barrier(0) pins all phase boundaries (r9/r19 lesson: compiler
//   resequencing collapses the pipeline).
// ---------------------------------------------------------------------------
__global__ __launch_bounds__(256, 5) void qkv_proj_mfma(
    const float* __restrict__ x, const unsigned short* __restrict__ WTf,
    unsigned short* __restrict__ Q, unsigned short* __restrict__ K,
    unsigned short* __restrict__ VT) {
  __shared__ __align__(16) unsigned short Bbuf[2][6144];  // 12 KB each, wave-private cols
  __shared__ __align__(16) unsigned short Abuf[4][640];   // [16][40] bf16 x 4

  const int tid = threadIdx.x;
  const int lane = tid & 63;
  const int w = tid >> 6;
  const int lr = lane & 15, lg = lane >> 4;
  const int row0 = blockIdx.x * 16;

  const int arow = tid >> 4, aunit = tid & 15;  // A-stage: row 0..15, 2-float unit
  const float* __restrict__ xsrc = x + (size_t)(row0 + arow) * NE + aunit * 2;

  f4v acc[3];
#pragma unroll
  for (int c = 0; c < 3; ++c) acc[c] = (f4v)0.f;

  float2 La[2];  // ring: load at t -> chunk t+3, consumed (cvtpk+write) at t+1

  auto ISSUE_B = [&](int buf, int t) {
#pragma unroll
    for (int j = 0; j < 3; ++j) {
      const int cb = w * 3 + j;
      glds16(WTf + (size_t)(cb * 32 + t) * 512 + lane * 8, &Bbuf[buf][cb * 512]);
    }
  };

  // ---- prologue: A(0),A(1) -> LDS; B(0) glds; chunk2 in flight in La[0]
  {
    const float2 l0 = *reinterpret_cast<const float2*>(xsrc);
    const float2 l1 = *reinterpret_cast<const float2*>(xsrc + 32);
    ISSUE_B(0, 0);
    La[0] = *reinterpret_cast<const float2*>(xsrc + 64);  // chunk 2
    *reinterpret_cast<unsigned*>(&Abuf[0][arow * 40 + aunit * 2]) =
        cvtpk(l0.x, l0.y);
    *reinterpret_cast<unsigned*>(&Abuf[1][arow * 40 + aunit * 2]) =
        cvtpk(l1.x, l1.y);
  }
  asm volatile("s_waitcnt vmcnt(1) lgkmcnt(0)" ::: "memory");
  __builtin_amdgcn_s_barrier();
  __builtin_amdgcn_sched_barrier(0);

#pragma unroll
  for (int t = 0; t < 32; ++t) {
    if (t + 1 < 32) ISSUE_B((t + 1) & 1, t + 1);   // B next tile (wave-private)
    __builtin_amdgcn_sched_barrier(0);
    if (t + 3 < 32)                                 // A chunk t+3 (HBM/L3)
      La[(t + 3) & 1] = *reinterpret_cast<const float2*>(xsrc + (t + 3) * 32);
    __builtin_amdgcn_sched_barrier(0);
    // ---- compute tile t
    const s8v a = *reinterpret_cast<const s8v*>(&Abuf[t % 4][lr * 40 + lg * 8]);
#pragma unroll
    for (int j = 0; j < 3; ++j) {
      const int cb = w * 3 + j;
      const s8v b =
          *reinterpret_cast<const s8v*>(&Bbuf[t & 1][cb * 512 + lane * 8]);
      acc[j] = __builtin_amdgcn_mfma_f32_16x16x32_bf16(a, b, acc[j], 0, 0, 0);
    }
    if (t + 2 < 32)  // write A(t+2) (chunk loaded at t-1) into slot (t+2)%4
      *reinterpret_cast<unsigned*>(&Abuf[(t + 2) % 4][arow * 40 + aunit * 2]) =
          cvtpk(La[t & 1].x, La[t & 1].y);
    __builtin_amdgcn_sched_barrier(0);
    if (t + 1 < 32) {
      if (t + 3 < 32) {  // newest load = A chunk t+3: keep it in flight
        asm volatile("s_waitcnt vmcnt(1) lgkmcnt(0)" ::: "memory");
      } else {           // tail: no A in flight -> full drain
        asm volatile("s_waitcnt vmcnt(0) lgkmcnt(0)" ::: "memory");
      }
      if (t & 1) __builtin_amdgcn_s_barrier();  // Abuf handoff: odd tiles only
      __builtin_amdgcn_sched_barrier(0);
    }
  }

  // ---- epilogue (Q pre-scaled into log2-softmax domain)
  const float QSCL = 0.18033688011112042f;  // 0.125 * log2(e)
#pragma unroll
  for (int c = 0; c < 3; ++c) {
    const int col = (w * 3 + c) * 16 + lr;
    const int m = col >> 6;  // uniform per (w,c)
    const int h = col & 63;
#pragma unroll
    for (int r = 0; r < 4; ++r) {
      const int rr = row0 + lg * 4 + r;  // D: row=(lane>>4)*4+reg
      if (m == 0) {
        Q[(size_t)rr * HH + h] = f2bf(acc[c][r] * QSCL);
      } else if (m == 1) {
        K[(size_t)rr * HH + h] = f2bf(acc[c][r]);
      } else {
        const int bb2 = rr >> 11, tt2 = rr & (TT - 1);
        VT[((size_t)bb2 * HH + h) * TT + tt2] = f2bf(acc[c][r]);
      }
    }
  }
}

// ---------------------------------------------------------------------------
// Kernel 2: causal flash attention — 512 threads (8 waves), k split 8 ways.
//   (r19 VERBATIM — measured ~24 µs, 32 waves/CU.  DO NOT TOUCH.)
// ---------------------------------------------------------------------------
__global__ __launch_bounds__(512, 4) void flash_attn_mfma(
    const unsigned short* __restrict__ Q, const unsigned short* __restrict__ K,
    const unsigned short* __restrict__ VT, float* __restrict__ out) {
  __shared__ float ol[8][16][64];   // 32 KB; ol[w] doubles as wave-w P-buffer
  __shared__ float ml[8][16];
  __shared__ float ll[8][16];

  const int tid = threadIdx.x;
  const int lane = tid & 63;
  const int w = tid >> 6;           // 0..7
  const int lr = lane & 15;
  const int lg = lane >> 4;
  const int bid = blockIdx.x;
  const int b = bid & 7;
  const int qt = 127 - (bid >> 3);  // LPT
  const int q0 = qt * 16;
  const size_t rowbase = (size_t)b * TT;

  unsigned short* const plw = reinterpret_cast<unsigned short*>(&ol[w][0][0]);
  // plw[row*72 + col], 2304 B < 4096 B of ol[w]

  const int nt = (qt >> 2) + 1;     // k-tiles of 64
  const int base = nt >> 3, rem = nt & 7;
  const int t0 = w * base + (w < rem ? w : rem);
  const int cnt = base + (w < rem ? 1 : 0);

  const s8v qf0 = *reinterpret_cast<const s8v*>(
      Q + (rowbase + q0 + lr) * HH + lg * 8);
  const s8v qf1 = *reinterpret_cast<const s8v*>(
      Q + (rowbase + q0 + lr) * HH + 32 + lg * 8);

  f4v o[4];
#pragma unroll
  for (int n = 0; n < 4; ++n) o[n] = (f4v)0.f;
  float mrow[4], lrow[4];
#pragma unroll
  for (int r = 0; r < 4; ++r) { mrow[r] = -INFINITY; lrow[r] = 0.f; }

  for (int kt = t0; kt < t0 + cnt; ++kt) {
    const int k0 = kt * 64;
    f4v s[4];
#pragma unroll
    for (int nk = 0; nk < 4; ++nk) s[nk] = (f4v)0.f;
    __builtin_amdgcn_s_setprio(1);
#pragma unroll
    for (int nk = 0; nk < 4; ++nk) {
      const unsigned short* kp = K + (rowbase + k0 + 16 * nk + lr) * HH + lg * 8;
      const s8v kf0 = *reinterpret_cast<const s8v*>(kp);
      const s8v kf1 = *reinterpret_cast<const s8v*>(kp + 32);
      s[nk] = __builtin_amdgcn_mfma_f32_16x16x32_bf16(qf0, kf0, s[nk], 0, 0, 0);
      s[nk] = __builtin_amdgcn_mfma_f32_16x16x32_bf16(qf1, kf1, s[nk], 0, 0, 0);
    }
    __builtin_amdgcn_s_setprio(0);
    // hoist V loads: L2 latency hides under softmax
    s8v vfr[2][4];
#pragma unroll
    for (int kh = 0; kh < 2; ++kh)
#pragma unroll
      for (int n = 0; n < 4; ++n)
        vfr[kh][n] = *reinterpret_cast<const s8v*>(
            VT + ((size_t)b * HH + 16 * n + lr) * TT + k0 + kh * 32 + lg * 8);

    // scores already log2-domain (Q pre-scaled); mask only on diag tile
    if (kt == nt - 1) {
#pragma unroll
      for (int nk = 0; nk < 4; ++nk) {
        const int kk = k0 + 16 * nk + lr;
#pragma unroll
        for (int r = 0; r < 4; ++r) {
          const int qq = q0 + lg * 4 + r;
          if (kk > qq) s[nk][r] = -INFINITY;
        }
      }
    }

    // row max (16-lane reduce) + T13 defer-max decision
    float mx_[4];
    float grow = -INFINITY;
#pragma unroll
    for (int r = 0; r < 4; ++r) {
      float mx = fmaxf(fmaxf(s[0][r], s[1][r]), fmaxf(s[2][r], s[3][r]));
#pragma unroll
      for (int off = 1; off < 16; off <<= 1)
        mx = fmaxf(mx, __shfl_xor(mx, off));
      mx_[r] = mx;
      grow = fmaxf(grow, mx - mrow[r]);
    }
    if (!__all(grow <= 8.f)) {  // wave-uniform rescale (rare after warmup)
#pragma unroll
      for (int r = 0; r < 4; ++r) {
        const float mnew = fmaxf(mrow[r], mx_[r]);
        const float scl = exp2f(mrow[r] - mnew);
        mrow[r] = mnew;
        lrow[r] *= scl;
#pragma unroll
        for (int n = 0; n < 4; ++n) o[n][r] *= scl;
      }
    }
    // p = exp2(s - m) (bounded by 2^8), shuffle row-sum
#pragma unroll
    for (int r = 0; r < 4; ++r) {
      float rs = 0.f;
#pragma unroll
      for (int nk = 0; nk < 4; ++nk) {
        const float p = exp2f(s[nk][r] - mrow[r]);
        s[nk][r] = p;
        rs += p;
      }
#pragma unroll
      for (int off = 1; off < 16; off <<= 1)
        rs += __shfl_xor(rs, off);
      lrow[r] += rs;
    }
    // P: D-layout -> per-wave LDS (aliased; wave-private, no barrier)
#pragma unroll
    for (int nk = 0; nk < 4; ++nk)
#pragma unroll
      for (int r = 0; r < 4; ++r)
        plw[(lg * 4 + r) * 72 + 16 * nk + lr] = f2bf_trunc(s[nk][r]);
    // PV
#pragma unroll
    for (int kh = 0; kh < 2; ++kh) {
      const int pc = kh * 32 + lg * 8;
      const ushort4 plo = *reinterpret_cast<const ushort4*>(&plw[lr * 72 + pc]);
      const ushort4 phi =
          *reinterpret_cast<const ushort4*>(&plw[lr * 72 + pc + 4]);
      s8v pa;
      pa[0] = plo.x; pa[1] = plo.y; pa[2] = plo.z; pa[3] = plo.w;
      pa[4] = phi.x; pa[5] = phi.y; pa[6] = phi.z; pa[7] = phi.w;
      __builtin_amdgcn_s_setprio(1);
#pragma unroll
      for (int n = 0; n < 4; ++n)
        o[n] = __builtin_amdgcn_mfma_f32_16x16x32_bf16(pa, vfr[kh][n], o[n], 0, 0, 0);
      __builtin_amdgcn_s_setprio(0);
    }
  }

  // publish per-wave partials (ol[w] overwrites this wave's own P-buffer)
  __syncthreads();
#pragma unroll
  for (int n = 0; n < 4; ++n)
#pragma unroll
    for (int r = 0; r < 4; ++r) ol[w][lg * 4 + r][16 * n + lr] = o[n][r];
  if (lr == 0) {
#pragma unroll
    for (int r = 0; r < 4; ++r) {
      ml[w][lg * 4 + r] = mrow[r];
      ll[w][lg * 4 + r] = lrow[r];
    }
  }
  __syncthreads();

  // 8-way combine: 512 threads -> (row = tid>>5, 2 cols at (tid&31)*2)
  const int row = tid >> 5;
  const int c0 = (tid & 31) * 2;
  float mw[8];
#pragma unroll
  for (int i = 0; i < 8; ++i) mw[i] = ml[i][row];
  float ms = mw[0];
#pragma unroll
  for (int i = 1; i < 8; ++i) ms = fmaxf(ms, mw[i]);
  // wave0 always has >= 1 tile -> ms finite; empty waves get weight 0
  float wt[8];
  float lsum = 0.f;
#pragma unroll
  for (int i = 0; i < 8; ++i) {
    wt[i] = exp2f(mw[i] - ms);
    lsum += wt[i] * ll[i][row];
  }
  float o0 = 0.f, o1 = 0.f;
#pragma unroll
  for (int i = 0; i < 8; ++i) {
    o0 += wt[i] * ol[i][row][c0 + 0];
    o1 += wt[i] * ol[i][row][c0 + 1];
  }
  const float inv = 1.0f / lsum;
  float2 res;
  res.x = o0 * inv;
  res.y = o1 * inv;
  *reinterpret_cast<float2*>(out + (rowbase + q0 + row) * HH + c0) = res;
}

extern "C" void kernel_launch(void* const* d_in, const int* in_sizes, int n_in,
                              void* d_out, int out_size, void* d_ws, size_t ws_size,
                              hipStream_t stream) {
  const float* x  = (const float*)d_in[0];
  const float* Wk = (const float*)d_in[1];
  const float* Wq = (const float*)d_in[2];
  const float* Wv = (const float*)d_in[3];
  float* out = (float*)d_out;

  unsigned short* ws = (unsigned short*)d_ws;
  unsigned short* Q  = ws;                           // BT*HH bf16
  unsigned short* K  = ws + (size_t)BT * HH;         // BT*HH bf16
  unsigned short* VT = ws + 2 * (size_t)BT * HH;     // B*HH*TT bf16
  unsigned short* WT = ws + 3 * (size_t)BT * HH;     // 192*1024 bf16 (frag-major)

  conv_wt_kernel<<<96, 256, 0, stream>>>(Wq, Wk, Wv, WT);
  qkv_proj_mfma<<<1024, 256, 0, stream>>>(x, WT, Q, K, VT);
  flash_attn_mfma<<<1024, 512, 0, stream>>>(Q, K, VT, out);
}